// Round 6
// baseline (177.611 us; speedup 1.0000x reference)
//
#include <hip/hip_runtime.h>

typedef __attribute__((ext_vector_type(8))) short          bf16x8;
typedef __attribute__((ext_vector_type(8))) unsigned short u16x8;
typedef __attribute__((ext_vector_type(4))) unsigned short u16x4;
typedef __attribute__((ext_vector_type(4))) float          f32x4;
typedef __attribute__((ext_vector_type(4))) unsigned int   u32x4;

union U8 { u16x8 u; bf16x8 b; u32x4 w; };
union U4 { u16x4 u; unsigned w[2]; };

__device__ __forceinline__ unsigned short f2bf(float f){
  unsigned u = __float_as_uint(f);
  return (unsigned short)((u + 0x7fffu + ((u >> 16) & 1u)) >> 16);
}
// pack two floats to bf16x2 (round-half-up): lo->low16, hi->high16. exact 0 preserved.
__device__ __forceinline__ unsigned pack_bf16(float lo, float hi){
  unsigned a = __float_as_uint(hi) + 0x8000u;
  unsigned b = __float_as_uint(lo) + 0x8000u;
  return __builtin_amdgcn_perm(a, b, 0x07060302u);
}

#define NN  1024
#define FIN 256
#define NH  8
#define FO  64

// ---------------------------------------------------------------------------
// Stage 0: wfrag = w in MFMA-B-frag-major layout (bf16); Abits = bit-packed A.
// wfrag element ((h*8+kc)*4+ss)*512 + lane*8 + j  <=  B[k=kc*32+(lane>>4)*8+j][o=16ss+(lane&15)]
// ---------------------------------------------------------------------------
__global__ __launch_bounds__(256) void stage0(
    const float* __restrict__ w, const int* __restrict__ A,
    unsigned short* __restrict__ wfrag, unsigned long long* __restrict__ Abits)
{
  const int tid = blockIdx.x * 256 + threadIdx.x;    // 1024 blocks -> 262144 thr
  if (tid < 16384){
    const int lane = tid & 63, ss = (tid >> 6) & 3, kc = (tid >> 8) & 7, h = tid >> 11;
    const int o = 16 * ss + (lane & 15);
    const int f = kc * 32 + (lane >> 4) * 8;
    u16x8 r;
    #pragma unroll
    for (int j = 0; j < 8; j++) r[j] = f2bf(w[(h * FIN + f + j) * FO + o]);
    *(u16x8*)(wfrag + tid * 8) = r;
  }
  for (int i = tid; i < 8388608; i += 262144){
    unsigned long long m = __ballot(A[i] > 0);
    if ((threadIdx.x & 63) == 0) Abits[i >> 6] = m;
  }
}

// ---------------------------------------------------------------------------
// Stage A: recx built in LDS per 32-row tile; h = recx @ w (MFMA, coalesced
// frag loads); panel stores hT[b,h,mtile,o,32] + exp tables.
// grid (32 tiles, 8 b), block 512 (8 waves = 8 heads).
// ---------------------------------------------------------------------------
__global__ __launch_bounds__(512, 4) void stageA(
    const float* __restrict__ x, const float* __restrict__ e_at,
    const float* __restrict__ Np, const unsigned short* __restrict__ wfrag,
    const float* __restrict__ a_src, const float* __restrict__ a_dst,
    unsigned short* __restrict__ hT,
    float* __restrict__ exps, float* __restrict__ exps2,
    float* __restrict__ expd, float* __restrict__ expd2)
{
  __shared__ unsigned short rex[32 * 264];   // 32 rows x 256 f, pad 264
  const int t = threadIdx.x;
  const int n0 = blockIdx.x * 32, b = blockIdx.y;

  {                                          // cooperative recx tile build
    const int row = t >> 4, f0 = (t & 15) * 16;
    const int nrow = n0 + row;
    const float* ep = e_at + (b * NN + nrow) * FIN + f0;
    const float* qp = Np + nrow * FIN + f0;
    const float* xp = x + b * FIN + f0;
    #pragma unroll
    for (int g = 0; g < 2; g++){
      f32x4 e0 = *(const f32x4*)(ep + g * 8), e1 = *(const f32x4*)(ep + g * 8 + 4);
      f32x4 q0 = *(const f32x4*)(qp + g * 8), q1 = *(const f32x4*)(qp + g * 8 + 4);
      f32x4 x0 = *(const f32x4*)(xp + g * 8), x1 = *(const f32x4*)(xp + g * 8 + 4);
      u16x8 r;
      #pragma unroll
      for (int j = 0; j < 4; j++){
        r[j]     = f2bf(e0[j] * q0[j] * x0[j]);
        r[j + 4] = f2bf(e1[j] * q1[j] * x1[j]);
      }
      *(u16x8*)(rex + row * 264 + f0 + g * 8) = r;
    }
  }
  __syncthreads();

  const int h = t >> 6, lane = t & 63, quad = lane >> 4, l15 = lane & 15;
  const unsigned short* wf = wfrag + h * 16384 + lane * 8;

  f32x4 acc[2][4] = {};
  #pragma unroll
  for (int kc = 0; kc < 8; kc++){
    U8 a0, a1, bf[4];
    a0.u = *(const u16x8*)(rex + l15 * 264 + kc * 32 + quad * 8);
    a1.u = *(const u16x8*)(rex + (16 + l15) * 264 + kc * 32 + quad * 8);
    #pragma unroll
    for (int ss = 0; ss < 4; ss++) bf[ss].u = *(const u16x8*)(wf + (kc * 4 + ss) * 512);
    #pragma unroll
    for (int ss = 0; ss < 4; ss++)
      acc[0][ss] = __builtin_amdgcn_mfma_f32_16x16x32_bf16(a0.b, bf[ss].b, acc[0][ss], 0, 0, 0);
    #pragma unroll
    for (int ss = 0; ss < 4; ss++)
      acc[1][ss] = __builtin_amdgcn_mfma_f32_16x16x32_bf16(a1.b, bf[ss].b, acc[1][ss], 0, 0, 0);
  }

  // panel store: [b,h,mtile,o(64),m(32)], C/D row(n)=quad*4+i, col(o)=16ss+l15
  {
    unsigned short* pan = hT + (size_t)(((b * NH + h) * 32 + (n0 >> 5)) * 64) * 32;
    #pragma unroll
    for (int rg = 0; rg < 2; rg++)
      #pragma unroll
      for (int ss = 0; ss < 4; ss++){
        U4 v;
        v.w[0] = pack_bf16(acc[rg][ss][0], acc[rg][ss][1]);
        v.w[1] = pack_bf16(acc[rg][ss][2], acc[rg][ss][3]);
        *(u16x4*)(pan + (16 * ss + l15) * 32 + rg * 16 + quad * 4) = v.u;
      }
  }

  // s/d reductions -> exp tables
  float as4[4], ad4[4];
  #pragma unroll
  for (int ss = 0; ss < 4; ss++){
    as4[ss] = a_src[h * FO + 16 * ss + l15];
    ad4[ss] = a_dst[h * FO + 16 * ss + l15];
  }
  #pragma unroll
  for (int rg = 0; rg < 2; rg++)
    #pragma unroll
    for (int i = 0; i < 4; i++){
      float ps = 0.f, pd = 0.f;
      #pragma unroll
      for (int ss = 0; ss < 4; ss++){ ps += acc[rg][ss][i] * as4[ss]; pd += acc[rg][ss][i] * ad4[ss]; }
      #pragma unroll
      for (int off = 1; off < 16; off <<= 1){
        ps += __shfl_xor(ps, off);
        pd += __shfl_xor(pd, off);
      }
      if (l15 == 0){
        const int idx = (b * NH + h) * NN + n0 + rg * 16 + quad * 4 + i;
        exps [idx] = __expf(ps);
        exps2[idx] = __expf(0.2f * ps);
        expd [idx] = __expf(pd);
        expd2[idx] = __expf(0.2f * pd);
      }
    }
}

// ---------------------------------------------------------------------------
// Stage B: fused masked-softmax aggregation.
// grid (32 tiles(32 rows), 8 b), block 1024 = 16 waves = 8 heads x 2 m-halves.
// Each wave: 32 rows (2 A-frags) x 512 m. True depth-2 prefetch (unroll-2,
// two named buffers, no copies). Partials merge via LDS atomics.
// ---------------------------------------------------------------------------
#define PCHUNK(C, PAN)                                                          \
  {                                                                             \
    const int c_ = (C);                                                         \
    const unsigned w0_ = mask_l[l15 * 33 + c_];                                 \
    const unsigned w1_ = mask_l[(16 + l15) * 33 + c_];                          \
    const unsigned ab0_ = w0_ >> (quad * 8), ab1_ = w1_ >> (quad * 8);          \
    f32x4 d0_ = *(const f32x4*)(edh + c_ * 32);                                 \
    f32x4 d1_ = *(const f32x4*)(edh + c_ * 32 + 4);                             \
    f32x4 g0_ = *(const f32x4*)(e2h + c_ * 32);                                 \
    f32x4 g1_ = *(const f32x4*)(e2h + c_ * 32 + 4);                             \
    U8 p0_, p1_;                                                                \
    _Pragma("unroll")                                                           \
    for (int r_ = 0; r_ < 4; r_++){                                             \
      const int j0_ = 2 * r_, j1_ = 2 * r_ + 1;                                 \
      const float dj0_ = (j0_ < 4) ? d0_[j0_] : d1_[j0_ - 4];                   \
      const float gj0_ = (j0_ < 4) ? g0_[j0_] : g1_[j0_ - 4];                   \
      const float dj1_ = (j1_ < 4) ? d0_[j1_] : d1_[j1_ - 4];                   \
      const float gj1_ = (j1_ < 4) ? g0_[j1_] : g1_[j1_ - 4];                   \
      float e00_ = fmaxf(Es0 * dj0_, Es20 * gj0_);                              \
      float e01_ = fmaxf(Es0 * dj1_, Es20 * gj1_);                              \
      float e10_ = fmaxf(Es1 * dj0_, Es21 * gj0_);                              \
      float e11_ = fmaxf(Es1 * dj1_, Es21 * gj1_);                              \
      e00_ = (ab0_ & (1u << j0_)) ? e00_ : 0.f;                                 \
      e01_ = (ab0_ & (1u << j1_)) ? e01_ : 0.f;                                 \
      e10_ = (ab1_ & (1u << j0_)) ? e10_ : 0.f;                                 \
      e11_ = (ab1_ & (1u << j1_)) ? e11_ : 0.f;                                 \
      p0_.w[r_] = pack_bf16(e00_, e01_);                                        \
      p1_.w[r_] = pack_bf16(e10_, e11_);                                        \
    }                                                                           \
    _Pragma("unroll")                                                           \
    for (int ss_ = 0; ss_ < 4; ss_++)                                           \
      acc[0][ss_] = __builtin_amdgcn_mfma_f32_16x16x32_bf16(p0_.b, PAN[ss_].b, acc[0][ss_], 0, 0, 0); \
    accs[0] = __builtin_amdgcn_mfma_f32_16x16x32_bf16(p0_.b, ones.b, accs[0], 0, 0, 0); \
    _Pragma("unroll")                                                           \
    for (int ss_ = 0; ss_ < 4; ss_++)                                           \
      acc[1][ss_] = __builtin_amdgcn_mfma_f32_16x16x32_bf16(p1_.b, PAN[ss_].b, acc[1][ss_], 0, 0, 0); \
    accs[1] = __builtin_amdgcn_mfma_f32_16x16x32_bf16(p1_.b, ones.b, accs[1], 0, 0, 0); \
  }

__global__ __launch_bounds__(1024, 4) void stageB(
    const unsigned* __restrict__ Aw,
    const unsigned short* __restrict__ hT,
    const float* __restrict__ exps, const float* __restrict__ exps2,
    const float* __restrict__ expd, const float* __restrict__ expd2,
    const float* __restrict__ bias, const float* __restrict__ mz,
    float* __restrict__ out)
{
  __shared__ float ed_l[NH * NN];        // 32 KB
  __shared__ float e2_l[NH * NN];        // 32 KB
  __shared__ unsigned mask_l[32 * 33];
  __shared__ float l_l[NH * 32];
  __shared__ float oacc[32 * 65];
  const int t = threadIdx.x, b = blockIdx.y, n0 = blockIdx.x * 32;
  const int h = (t >> 6) & 7, mh = t >> 9;
  const int lane = t & 63, quad = lane >> 4, l15 = lane & 15;

  for (int i = t; i < 32 * 65; i += 1024) oacc[i] = 0.f;
  if (t < NH * 32) l_l[t] = 0.f;
  {                                       // exp-table preload (coalesced)
    const float* s1 = expd  + b * 8192;
    const float* s2 = expd2 + b * 8192;
    *(f32x4*)(ed_l + t * 4)        = *(const f32x4*)(s1 + t * 4);
    *(f32x4*)(ed_l + t * 4 + 4096) = *(const f32x4*)(s1 + t * 4 + 4096);
    *(f32x4*)(e2_l + t * 4)        = *(const f32x4*)(s2 + t * 4);
    *(f32x4*)(e2_l + t * 4 + 4096) = *(const f32x4*)(s2 + t * 4 + 4096);
  }
  mask_l[(t >> 5) * 33 + (t & 31)] = Aw[(b * NN + n0 + (t >> 5)) * 32 + (t & 31)];
  __syncthreads();

  const int hb = (b * NH + h) * NN;
  const float Es0  = exps [hb + n0 + l15],      Es20 = exps2[hb + n0 + l15];
  const float Es1  = exps [hb + n0 + 16 + l15], Es21 = exps2[hb + n0 + 16 + l15];
  const unsigned short* pb = hT + (size_t)(b * NH + h) * 65536 + l15 * 32 + quad * 8;
  const float* edh = ed_l + h * NN + quad * 8;
  const float* e2h = e2_l + h * NN + quad * 8;
  const int c0 = mh * 16;                 // this wave's m-half

  U8 ones;
  #pragma unroll
  for (int j = 0; j < 8; j++) ones.u[j] = 0x3F80;

  U8 pan0[4], pan1[4];
  #pragma unroll
  for (int ss = 0; ss < 4; ss++){
    pan0[ss].u = *(const u16x8*)(pb + (size_t)c0 * 2048 + ss * 512);
    pan1[ss].u = *(const u16x8*)(pb + (size_t)(c0 + 1) * 2048 + ss * 512);
  }

  f32x4 acc[2][4] = {};
  f32x4 accs[2] = {};

  for (int cc = 0; cc < 16; cc += 2){
    PCHUNK(c0 + cc, pan0)
    if (cc + 2 < 16){
      #pragma unroll
      for (int ss = 0; ss < 4; ss++)
        pan0[ss].u = *(const u16x8*)(pb + (size_t)(c0 + cc + 2) * 2048 + ss * 512);
    }
    PCHUNK(c0 + cc + 1, pan1)
    if (cc + 3 < 16){
      #pragma unroll
      for (int ss = 0; ss < 4; ss++)
        pan1[ss].u = *(const u16x8*)(pb + (size_t)(c0 + cc + 3) * 2048 + ss * 512);
    }
  }

  // partial row sums -> l_l (accs lanes carry identical col values)
  if (l15 == 0){
    #pragma unroll
    for (int rg = 0; rg < 2; rg++)
      #pragma unroll
      for (int i = 0; i < 4; i++)
        atomicAdd(&l_l[h * 32 + rg * 16 + quad * 4 + i], accs[rg][i]);
  }
  __syncthreads();

  // normalize + merge partial aggregates
  #pragma unroll
  for (int rg = 0; rg < 2; rg++){
    float inv[4];
    #pragma unroll
    for (int i = 0; i < 4; i++)
      inv[i] = 0.125f / l_l[h * 32 + rg * 16 + quad * 4 + i];
    #pragma unroll
    for (int ss = 0; ss < 4; ss++)
      #pragma unroll
      for (int i = 0; i < 4; i++)
        atomicAdd(&oacc[(rg * 16 + quad * 4 + i) * 65 + ss * 16 + l15], acc[rg][ss][i] * inv[i]);
  }
  __syncthreads();

  for (int i = t; i < 2048; i += 1024){
    const int r = i >> 6, o = i & 63;
    out[(b * NN + n0 + r) * FO + o] = (oacc[r * 65 + o] + bias[o]) * mz[b * NN + n0 + r];
  }
}

extern "C" void kernel_launch(void* const* d_in, const int* in_sizes, int n_in,
                              void* d_out, int out_size, void* d_ws, size_t ws_size,
                              hipStream_t stream)
{
  (void)in_sizes; (void)n_in; (void)out_size; (void)ws_size;
  const float* x    = (const float*)d_in[0];
  const int*   A    = (const int*)d_in[1];
  const float* mz   = (const float*)d_in[2];
  const float* e_at = (const float*)d_in[4];
  const float* Np   = (const float*)d_in[5];
  const float* w    = (const float*)d_in[6];
  const float* asrc = (const float*)d_in[7];
  const float* adst = (const float*)d_in[8];
  const float* bias = (const float*)d_in[9];
  float* out = (float*)d_out;

  char* ws = (char*)d_ws;
  unsigned short* wfrag = (unsigned short*)ws;                     // 256 KB
  unsigned short* hT    = (unsigned short*)(ws + 262144);          // 8 MB
  float* exps  = (float*)(ws + 8650752);                           // 256 KB
  float* exps2 = (float*)(ws + 8912896);                           // 256 KB
  float* expd  = (float*)(ws + 9175040);                           // 256 KB
  float* expd2 = (float*)(ws + 9437184);                           // 256 KB
  unsigned long long* Abits = (unsigned long long*)(ws + 9699328); // 1 MB

  stage0<<<dim3(1024), dim3(256), 0, stream>>>(w, A, wfrag, Abits);
  stageA<<<dim3(32, 8), dim3(512), 0, stream>>>(x, e_at, Np, wfrag, asrc, adst,
                                                hT, exps, exps2, expd, expd2);
  stageB<<<dim3(32, 8), dim3(1024), 0, stream>>>((const unsigned*)Abits, hT,
                                                 exps, exps2, expd, expd2,
                                                 bias, mz, out);
}

// Round 7
// 170.405 us; speedup vs baseline: 1.0423x; 1.0423x over previous
//
#include <hip/hip_runtime.h>

typedef __attribute__((ext_vector_type(8))) short          bf16x8;
typedef __attribute__((ext_vector_type(8))) unsigned short u16x8;
typedef __attribute__((ext_vector_type(4))) unsigned short u16x4;
typedef __attribute__((ext_vector_type(4))) float          f32x4;
typedef __attribute__((ext_vector_type(4))) unsigned int   u32x4;

union U8 { u16x8 u; bf16x8 b; u32x4 w; };
union U4 { u16x4 u; unsigned w[2]; };

__device__ __forceinline__ unsigned short f2bf(float f){
  unsigned u = __float_as_uint(f);
  return (unsigned short)((u + 0x7fffu + ((u >> 16) & 1u)) >> 16);
}
// pack two floats to bf16x2 (round-half-up): lo->low16, hi->high16. exact 0 preserved.
__device__ __forceinline__ unsigned pack_bf16(float lo, float hi){
  unsigned a = __float_as_uint(hi) + 0x8000u;
  unsigned b = __float_as_uint(lo) + 0x8000u;
  return __builtin_amdgcn_perm(a, b, 0x07060302u);
}

#define NN  1024
#define FIN 256
#define NH  8
#define FO  64

// ---------------------------------------------------------------------------
// Stage 0: wfrag = w in MFMA-B-frag layout; Abits = bit-packed A;
//          out = bias*mz (pre-init for stageB's atomic head-merge).
// grid 1024 x 256
// ---------------------------------------------------------------------------
__global__ __launch_bounds__(256) void stage0(
    const float* __restrict__ w, const int* __restrict__ A,
    const float* __restrict__ bias, const float* __restrict__ mz,
    unsigned short* __restrict__ wfrag, unsigned long long* __restrict__ Abits,
    float* __restrict__ out)
{
  const int tid = blockIdx.x * 256 + threadIdx.x;    // 262144 threads
  if (tid < 16384){
    const int lane = tid & 63, ss = (tid >> 6) & 3, kc = (tid >> 8) & 7, h = tid >> 11;
    const int o = 16 * ss + (lane & 15);
    const int f = kc * 32 + (lane >> 4) * 8;
    u16x8 r;
    #pragma unroll
    for (int j = 0; j < 8; j++) r[j] = f2bf(w[(h * FIN + f + j) * FO + o]);
    *(u16x8*)(wfrag + tid * 8) = r;
  }
  #pragma unroll
  for (int k = 0; k < 2; k++){                       // out = bias*mz
    const int i = tid + k * 262144;
    out[i] = bias[i & 63] * mz[i >> 6];
  }
  for (int i = tid; i < 8388608; i += 262144){       // adjacency bit-pack
    unsigned long long m = __ballot(A[i] > 0);
    if ((threadIdx.x & 63) == 0) Abits[i >> 6] = m;
  }
}

// ---------------------------------------------------------------------------
// Stage A: recx built in LDS per 16-row tile; h = recx @ w (MFMA);
// panel stores hT[b,h,mtile,o,32] + exp tables.
// grid (64 tiles(16 rows), 8 b) = 512 blocks, block 512 (8 waves = 8 heads).
// ---------------------------------------------------------------------------
__global__ __launch_bounds__(512, 4) void stageA(
    const float* __restrict__ x, const float* __restrict__ e_at,
    const float* __restrict__ Np, const unsigned short* __restrict__ wfrag,
    const float* __restrict__ a_src, const float* __restrict__ a_dst,
    unsigned short* __restrict__ hT,
    float* __restrict__ exps, float* __restrict__ exps2,
    float* __restrict__ expd, float* __restrict__ expd2)
{
  __shared__ unsigned short rex[16 * 264];   // 16 rows x 256 f, pad 264
  const int t = threadIdx.x;
  const int n0 = blockIdx.x * 16, b = blockIdx.y;

  {                                          // cooperative recx tile build
    const int row = t >> 5, f0 = (t & 31) * 8;
    const int nrow = n0 + row;
    const float* ep = e_at + (b * NN + nrow) * FIN + f0;
    const float* qp = Np + nrow * FIN + f0;
    const float* xp = x + b * FIN + f0;
    f32x4 e0 = *(const f32x4*)ep, e1 = *(const f32x4*)(ep + 4);
    f32x4 q0 = *(const f32x4*)qp, q1 = *(const f32x4*)(qp + 4);
    f32x4 x0 = *(const f32x4*)xp, x1 = *(const f32x4*)(xp + 4);
    u16x8 r;
    #pragma unroll
    for (int j = 0; j < 4; j++){
      r[j]     = f2bf(e0[j] * q0[j] * x0[j]);
      r[j + 4] = f2bf(e1[j] * q1[j] * x1[j]);
    }
    *(u16x8*)(rex + row * 264 + f0) = r;
  }
  __syncthreads();

  const int h = t >> 6, lane = t & 63, quad = lane >> 4, l15 = lane & 15;
  const unsigned short* wf = wfrag + h * 16384 + lane * 8;

  f32x4 acc[4] = {};
  #pragma unroll
  for (int kc = 0; kc < 8; kc++){
    U8 a0, bf[4];
    a0.u = *(const u16x8*)(rex + l15 * 264 + kc * 32 + quad * 8);
    #pragma unroll
    for (int ss = 0; ss < 4; ss++) bf[ss].u = *(const u16x8*)(wf + (kc * 4 + ss) * 512);
    #pragma unroll
    for (int ss = 0; ss < 4; ss++)
      acc[ss] = __builtin_amdgcn_mfma_f32_16x16x32_bf16(a0.b, bf[ss].b, acc[ss], 0, 0, 0);
  }

  // panel store: [b,h,mtile,o(64),m(32)], C/D row(n)=quad*4+i, col(o)=16ss+l15
  {
    const int mtile = blockIdx.x >> 1, moff = (blockIdx.x & 1) * 16;
    unsigned short* pan = hT + (size_t)(((b * NH + h) * 32 + mtile) * 64) * 32;
    #pragma unroll
    for (int ss = 0; ss < 4; ss++){
      U4 v;
      v.w[0] = pack_bf16(acc[ss][0], acc[ss][1]);
      v.w[1] = pack_bf16(acc[ss][2], acc[ss][3]);
      *(u16x4*)(pan + (16 * ss + l15) * 32 + moff + quad * 4) = v.u;
    }
  }

  // s/d reductions -> exp tables
  float as4[4], ad4[4];
  #pragma unroll
  for (int ss = 0; ss < 4; ss++){
    as4[ss] = a_src[h * FO + 16 * ss + l15];
    ad4[ss] = a_dst[h * FO + 16 * ss + l15];
  }
  #pragma unroll
  for (int i = 0; i < 4; i++){
    float ps = 0.f, pd = 0.f;
    #pragma unroll
    for (int ss = 0; ss < 4; ss++){ ps += acc[ss][i] * as4[ss]; pd += acc[ss][i] * ad4[ss]; }
    #pragma unroll
    for (int off = 1; off < 16; off <<= 1){
      ps += __shfl_xor(ps, off);
      pd += __shfl_xor(pd, off);
    }
    if (l15 == 0){
      const int idx = (b * NH + h) * NN + n0 + quad * 4 + i;
      exps [idx] = __expf(ps);
      exps2[idx] = __expf(0.2f * ps);
      expd [idx] = __expf(pd);
      expd2[idx] = __expf(0.2f * pd);
    }
  }
}

// ---------------------------------------------------------------------------
// Stage B: fused masked-softmax aggregation, occupancy-first.
// grid (32 tiles(32 rows), 4 head-pairs, 8 b) = 1024 blocks, block 512
// (8 waves = 2 heads x 2 row-groups x 2 m-halves). 4 blocks/CU = 32 waves/CU.
// Head merge via global fp32 atomics into pre-initialized out.
// ---------------------------------------------------------------------------
__global__ __launch_bounds__(512, 8) void stageB(
    const unsigned* __restrict__ Aw,
    const unsigned short* __restrict__ hT,
    const float* __restrict__ exps, const float* __restrict__ exps2,
    const float* __restrict__ expd, const float* __restrict__ expd2,
    const float* __restrict__ mz, float* __restrict__ out)
{
  __shared__ float ed_l[2 * NN];         // 8 KB (2 heads)
  __shared__ float e2_l[2 * NN];         // 8 KB
  __shared__ unsigned mask_l[32 * 33];   // 4.2 KB
  __shared__ float l_l[4 * 16];          // (hl,rg) x 16 rows
  const int t = threadIdx.x;
  const int n0 = blockIdx.x * 32, hq = blockIdx.y, b = blockIdx.z;
  const int w = t >> 6, lane = t & 63, quad = lane >> 4, l15 = lane & 15;
  const int hl = w & 1, rg = (w >> 1) & 1, mh = w >> 2;
  const int h = hq * 2 + hl;

  if (t < 64) l_l[t] = 0.f;
  {                                      // exp-table preload (coalesced)
    const float* s1 = expd  + (b * NH + hq * 2) * NN;
    const float* s2 = expd2 + (b * NH + hq * 2) * NN;
    *(f32x4*)(ed_l + t * 4) = *(const f32x4*)(s1 + t * 4);
    *(f32x4*)(e2_l + t * 4) = *(const f32x4*)(s2 + t * 4);
  }
  #pragma unroll
  for (int k = 0; k < 2; k++){
    const int i = t + k * 512;
    mask_l[(i >> 5) * 33 + (i & 31)] = Aw[(b * NN + n0 + (i >> 5)) * 32 + (i & 31)];
  }
  __syncthreads();

  const int hb = (b * NH + h) * NN;
  const float Es  = exps [hb + n0 + rg * 16 + l15];
  const float Es2 = exps2[hb + n0 + rg * 16 + l15];
  const unsigned short* pb = hT + (size_t)(b * NH + h) * 65536 + l15 * 32 + quad * 8;
  const float* edh = ed_l + hl * NN + quad * 8;
  const float* e2h = e2_l + hl * NN + quad * 8;
  const unsigned* maskp = mask_l + (rg * 16 + l15) * 33;
  const int c0 = mh * 16;

  U8 pan[4];
  #pragma unroll
  for (int ss = 0; ss < 4; ss++)
    pan[ss].u = *(const u16x8*)(pb + (size_t)c0 * 2048 + ss * 512);

  f32x4 acc[4] = {};
  float lp = 0.f;

  for (int cc = 0; cc < 16; cc++){
    const int c = c0 + cc;
    const unsigned am = maskp[c] >> (quad * 8);
    float pv[8];
    #pragma unroll
    for (int g2 = 0; g2 < 2; g2++){
      f32x4 dv = *(const f32x4*)(edh + c * 32 + g2 * 4);
      f32x4 gv = *(const f32x4*)(e2h + c * 32 + g2 * 4);
      #pragma unroll
      for (int j = 0; j < 4; j++){
        float e = fmaxf(Es * dv[j], Es2 * gv[j]);
        pv[g2 * 4 + j] = (am & (1u << (g2 * 4 + j))) ? e : 0.f;
      }
    }
    lp += ((pv[0] + pv[1]) + (pv[2] + pv[3])) + ((pv[4] + pv[5]) + (pv[6] + pv[7]));
    U8 p;
    #pragma unroll
    for (int r = 0; r < 4; r++) p.w[r] = pack_bf16(pv[2 * r], pv[2 * r + 1]);
    #pragma unroll
    for (int ss = 0; ss < 4; ss++)
      acc[ss] = __builtin_amdgcn_mfma_f32_16x16x32_bf16(p.b, pan[ss].b, acc[ss], 0, 0, 0);
    if (cc + 1 < 16){
      #pragma unroll
      for (int ss = 0; ss < 4; ss++)
        pan[ss].u = *(const u16x8*)(pb + (size_t)(c + 1) * 2048 + ss * 512);
    }
  }

  // lane's lp = row l15's partial over this quad's cols; reduce quads + m-halves
  lp += __shfl_xor(lp, 16);
  lp += __shfl_xor(lp, 32);
  if (lane < 16) atomicAdd(&l_l[(w & 3) * 16 + lane], lp);
  __syncthreads();

  // normalize (1/8 folded) * mz, merge heads via global atomics
  const float* mzp = mz + b * NN + n0 + rg * 16;
  #pragma unroll
  for (int i = 0; i < 4; i++){
    const int row = quad * 4 + i;
    const float invm = (0.125f / l_l[(w & 3) * 16 + row]) * mzp[row];
    float* op = out + (size_t)(b * NN + n0 + rg * 16 + row) * FO + l15;
    #pragma unroll
    for (int ss = 0; ss < 4; ss++)
      atomicAdd(op + ss * 16, acc[ss][i] * invm);
  }
}

extern "C" void kernel_launch(void* const* d_in, const int* in_sizes, int n_in,
                              void* d_out, int out_size, void* d_ws, size_t ws_size,
                              hipStream_t stream)
{
  (void)in_sizes; (void)n_in; (void)out_size; (void)ws_size;
  const float* x    = (const float*)d_in[0];
  const int*   A    = (const int*)d_in[1];
  const float* mz   = (const float*)d_in[2];
  const float* e_at = (const float*)d_in[4];
  const float* Np   = (const float*)d_in[5];
  const float* w    = (const float*)d_in[6];
  const float* asrc = (const float*)d_in[7];
  const float* adst = (const float*)d_in[8];
  const float* bias = (const float*)d_in[9];
  float* out = (float*)d_out;

  char* ws = (char*)d_ws;
  unsigned short* wfrag = (unsigned short*)ws;                     // 256 KB
  unsigned short* hT    = (unsigned short*)(ws + 262144);          // 8 MB
  float* exps  = (float*)(ws + 8650752);                           // 256 KB
  float* exps2 = (float*)(ws + 8912896);                           // 256 KB
  float* expd  = (float*)(ws + 9175040);                           // 256 KB
  float* expd2 = (float*)(ws + 9437184);                           // 256 KB
  unsigned long long* Abits = (unsigned long long*)(ws + 9699328); // 1 MB

  stage0<<<dim3(1024), dim3(256), 0, stream>>>(w, A, bias, mz, wfrag, Abits, out);
  stageA<<<dim3(64, 8), dim3(512), 0, stream>>>(x, e_at, Np, wfrag, asrc, adst,
                                                hT, exps, exps2, expd, expd2);
  stageB<<<dim3(32, 4, 8), dim3(512), 0, stream>>>((const unsigned*)Abits, hT,
                                                   exps, exps2, expd, expd2,
                                                   mz, out);
}